// Round 2
// baseline (16.283 us; speedup 1.0000x reference)
//
#include <hip/hip_runtime.h>

#define IS     192
#define F_CNT  512
#define TEX    4
#define NEARF  0.1f
#define FARF   100.0f
#define TSZ    8      // tile size (8x8 pixels, 64 threads = 1 wave per block)
#define CAP    256    // LDS-cached compacted candidates (expected ~13/tile)

struct alignas(16) FaceData {
    float xmin, xmax, ymin, ymax;                        // bbox
    float x0, y0, x1, y1, x2, y2;                        // xy verts
    float f00, f01, f02, f10, f11, f12, f20, f21, f22;   // face_inv rows
    float iz0, iz1, iz2;                                 // 1/z per vert
    float z0, z1, z2;                                    // z per vert
    float pad0, pad1, pad2;                              // pad to 28 floats
};

// Build FaceData from 9 vertex floats — expressions must stay bit-identical
// to the reference order (rows computed, then each element divided by det).
__device__ inline FaceData make_face(const float* __restrict__ v) {
    FaceData fd;
    const float x0 = v[0], y0 = v[1], z0 = v[2];
    const float x1 = v[3], y1 = v[4], z1 = v[5];
    const float x2 = v[6], y2 = v[7], z2 = v[8];

    fd.xmin = fminf(x0, fminf(x1, x2));
    fd.xmax = fmaxf(x0, fmaxf(x1, x2));
    fd.ymin = fminf(y0, fminf(y1, y2));
    fd.ymax = fmaxf(y0, fmaxf(y1, y2));
    fd.x0 = x0; fd.y0 = y0; fd.x1 = x1; fd.y1 = y1; fd.x2 = x2; fd.y2 = y2;

    float det = x2 * (y0 - y1) + x0 * (y1 - y2) + x1 * (y2 - y0);
    if (fabsf(det) < 1e-12f) det = 1e-12f;
    fd.f00 = (y1 - y2) / det;
    fd.f01 = (x2 - x1) / det;
    fd.f02 = (x1 * y2 - x2 * y1) / det;
    fd.f10 = (y2 - y0) / det;
    fd.f11 = (x0 - x2) / det;
    fd.f12 = (x2 * y0 - x0 * y2) / det;
    fd.f20 = (y0 - y1) / det;
    fd.f21 = (x1 - x0) / det;
    fd.f22 = (x0 * y1 - x1 * y0) / det;

    fd.iz0 = 1.0f / z0; fd.iz1 = 1.0f / z1; fd.iz2 = 1.0f / z2;
    fd.z0 = z0; fd.z1 = z1; fd.z2 = z2;
    return fd;
}

__global__ __launch_bounds__(64) void raster_kernel(
    const float* __restrict__ faces,
    const float* __restrict__ textures,
    float* __restrict__ out)
{
    __shared__ FaceData sf[CAP];
    __shared__ unsigned short sidx[F_CNT];
    __shared__ int scount;

    const int b   = blockIdx.z;
    const int tx0 = blockIdx.x * TSZ;
    const int ty0 = blockIdx.y * TSZ;
    const int tid = threadIdx.y * TSZ + threadIdx.x;

    if (tid == 0) scount = 0;
    __syncthreads();

    // tile bbox in NDC (pixel centers): coord = (2*i + 1 - IS) / IS
    const float xlo = (2.0f * tx0             + 1.0f - IS) / (float)IS;
    const float xhi = (2.0f * (tx0 + TSZ - 1) + 1.0f - IS) / (float)IS;
    const float ylo = (2.0f * ty0             + 1.0f - IS) / (float)IS;
    const float yhi = (2.0f * (ty0 + TSZ - 1) + 1.0f - IS) / (float)IS;

    // ---- scan all faces, compact tile-overlapping front faces ----
    for (int f = tid; f < F_CNT; f += 64) {
        const float* v = faces + ((size_t)b * F_CNT + f) * 9;
        const float x0 = v[0], y0 = v[1];
        const float x1 = v[3], y1 = v[4];
        const float x2 = v[6], y2 = v[7];

        // backface cull: front iff (y2-y0)*(x1-x0) >= (x2-x0)*(y1-y0)
        const bool front = (y2 - y0) * (x1 - x0) >= (x2 - x0) * (y1 - y0);

        const float bxmin = fminf(x0, fminf(x1, x2));
        const float bxmax = fmaxf(x0, fmaxf(x1, x2));
        const float bymin = fminf(y0, fminf(y1, y2));
        const float bymax = fmaxf(y0, fmaxf(y1, y2));

        const bool keep = front &&
                          bxmin <= xhi && bxmax >= xlo &&
                          bymin <= yhi && bymax >= ylo;
        if (keep) {
            const int slot = atomicAdd(&scount, 1);
            sidx[slot] = (unsigned short)f;
            if (slot < CAP) sf[slot] = make_face(v);
        }
    }
    __syncthreads();

    // ---- per-pixel rasterization ----
    const int px = tx0 + threadIdx.x;
    const int py = ty0 + threadIdx.y;
    const float xp = (2.0f * px + 1.0f - IS) / (float)IS;
    const float yp = (2.0f * py + 1.0f - IS) / (float)IS;

    float best = FARF;
    int bestf = -1;
    float bw0 = 0.0f, bw1 = 0.0f, bw2 = 0.0f;
    float bz0 = 1.0f, bz1 = 1.0f, bz2 = 1.0f;

    // loop body: test one face; selection uses the (zp, f) total order so the
    // result is independent of the (atomic, unordered) compaction order
    auto process = [&](const FaceData& fd, const int f) {
        if (xp < fd.xmin || xp > fd.xmax || yp < fd.ymin || yp > fd.ymax) return;

        const bool in01 = (yp - fd.y0) * (fd.x1 - fd.x0) >= (xp - fd.x0) * (fd.y1 - fd.y0);
        const bool in12 = (yp - fd.y1) * (fd.x2 - fd.x1) >= (xp - fd.x1) * (fd.y2 - fd.y1);
        const bool in20 = (yp - fd.y2) * (fd.x0 - fd.x2) >= (xp - fd.x2) * (fd.y0 - fd.y2);
        if (!(in01 && in12 && in20)) return;

        float w0 = fd.f00 * xp + fd.f01 * yp + fd.f02;
        float w1 = fd.f10 * xp + fd.f11 * yp + fd.f12;
        float w2 = fd.f20 * xp + fd.f21 * yp + fd.f22;
        w0 = fminf(fmaxf(w0, 0.0f), 1.0f);
        w1 = fminf(fmaxf(w1, 0.0f), 1.0f);
        w2 = fminf(fmaxf(w2, 0.0f), 1.0f);
        const float ws = fmaxf(w0 + w1 + w2, 1e-12f);
        w0 = w0 / ws; w1 = w1 / ws; w2 = w2 / ws;

        const float s = w0 * fd.iz0 + w1 * fd.iz1 + w2 * fd.iz2;
        const float zp = 1.0f / fmaxf(s, 1e-12f);

        if (zp > NEARF && zp < FARF) {
            if (zp < best || (zp == best && f < bestf)) {
                best = zp; bestf = f;
                bw0 = w0; bw1 = w1; bw2 = w2;
                bz0 = fd.z0; bz1 = fd.z1; bz2 = fd.z2;
            }
        }
    };

    const int cnt = scount;
    const int ncached = (cnt < CAP) ? cnt : CAP;
    for (int i = 0; i < ncached; ++i)
        process(sf[i], sidx[i]);
    for (int i = CAP; i < cnt; ++i) {  // overflow fallback (never taken for this input)
        const int f = sidx[i];
        const FaceData fd = make_face(faces + ((size_t)b * F_CNT + f) * 9);
        process(fd, f);
    }

    // ---- texture-cube trilinear sampling for the winning face ----
    float r = 0.0f, g = 0.0f, bc = 0.0f;
    if (bestf >= 0) {
        // tif = (w * (T-1)) * (depth / z)  -- same assoc order as reference
        float t0 = bw0 * 3.0f * (best / bz0);
        float t1 = bw1 * 3.0f * (best / bz1);
        float t2 = bw2 * 3.0f * (best / bz2);
        const float tmax = 2.999f;  // T - 1 - EPS
        t0 = fminf(fmaxf(t0, 0.0f), tmax);
        t1 = fminf(fmaxf(t1, 0.0f), tmax);
        t2 = fminf(fmaxf(t2, 0.0f), tmax);
        const float fl0 = floorf(t0), fl1 = floorf(t1), fl2 = floorf(t2);
        const float fr0 = t0 - fl0, fr1 = t1 - fl1, fr2 = t2 - fl2;
        const int i0 = (int)fl0, i1 = (int)fl1, i2 = (int)fl2;

        const float* tex = textures + ((size_t)b * F_CNT + bestf) * (TEX * TEX * TEX * 3);
        #pragma unroll
        for (int c = 0; c < 8; ++c) {
            const int b0 = c & 1, b1 = (c >> 1) & 1, b2 = (c >> 2) & 1;
            const float cw = (b0 ? fr0 : 1.0f - fr0)
                           * (b1 ? fr1 : 1.0f - fr1)
                           * (b2 ? fr2 : 1.0f - fr2);
            const float* sp = tex + (((size_t)(i0 + b0) * TEX + (i1 + b1)) * TEX + (i2 + b2)) * 3;
            r  += cw * sp[0];
            g  += cw * sp[1];
            bc += cw * sp[2];
        }
    }

    // ---- writes: rgb [B,IS,IS,3] | alpha [B,1,IS,IS] | depth [B,IS,IS] ----
    const size_t pix = (size_t)py * IS + px;
    const size_t bp  = (size_t)b * IS * IS + pix;

    out[bp * 3 + 0] = r;
    out[bp * 3 + 1] = g;
    out[bp * 3 + 2] = bc;

    float* alpha = out + (size_t)2 * IS * IS * 3;   // after rgb (both batches)
    alpha[bp] = (bestf >= 0) ? 1.0f : 0.0f;

    float* depth = alpha + (size_t)2 * IS * IS;
    depth[bp] = best;  // FAR when no face found
}

extern "C" void kernel_launch(void* const* d_in, const int* in_sizes, int n_in,
                              void* d_out, int out_size, void* d_ws, size_t ws_size,
                              hipStream_t stream) {
    const float* faces    = (const float*)d_in[0];
    const float* textures = (const float*)d_in[1];
    float* out = (float*)d_out;

    const int B = in_sizes[0] / (F_CNT * 9);  // = 2

    dim3 grid(IS / TSZ, IS / TSZ, B);
    dim3 block(TSZ, TSZ, 1);
    raster_kernel<<<grid, block, 0, stream>>>(faces, textures, out);
}

// Round 3
// 14.310 us; speedup vs baseline: 1.1379x; 1.1379x over previous
//
#include <hip/hip_runtime.h>

#define IS     192
#define F_CNT  512
#define TEX    4
#define NEARF  0.1f
#define FARF   100.0f
#define RW     32     // region width  (pixels)
#define RH     16     // region height (pixels)
#define CAP    256    // LDS-cached compacted candidates (expected ~16/region)

struct alignas(16) FaceData {
    float xmin, xmax, ymin, ymax;                        // bbox
    float x0, y0, x1, y1, x2, y2;                        // xy verts
    float f00, f01, f02, f10, f11, f12, f20, f21, f22;   // face_inv rows
    float iz0, iz1, iz2;                                 // 1/z per vert
    float z0, z1, z2;                                    // z per vert
    float pad0, pad1, pad2;                              // pad to 28 floats
};

// Build FaceData from 9 vertex floats — expressions bit-identical to the
// reference order (rows computed, then each element divided by det).
__device__ inline FaceData make_face(const float* __restrict__ v) {
    FaceData fd;
    const float x0 = v[0], y0 = v[1], z0 = v[2];
    const float x1 = v[3], y1 = v[4], z1 = v[5];
    const float x2 = v[6], y2 = v[7], z2 = v[8];

    fd.xmin = fminf(x0, fminf(x1, x2));
    fd.xmax = fmaxf(x0, fmaxf(x1, x2));
    fd.ymin = fminf(y0, fminf(y1, y2));
    fd.ymax = fmaxf(y0, fmaxf(y1, y2));
    fd.x0 = x0; fd.y0 = y0; fd.x1 = x1; fd.y1 = y1; fd.x2 = x2; fd.y2 = y2;

    float det = x2 * (y0 - y1) + x0 * (y1 - y2) + x1 * (y2 - y0);
    if (fabsf(det) < 1e-12f) det = 1e-12f;
    fd.f00 = (y1 - y2) / det;
    fd.f01 = (x2 - x1) / det;
    fd.f02 = (x1 * y2 - x2 * y1) / det;
    fd.f10 = (y2 - y0) / det;
    fd.f11 = (x0 - x2) / det;
    fd.f12 = (x2 * y0 - x0 * y2) / det;
    fd.f20 = (y0 - y1) / det;
    fd.f21 = (x1 - x0) / det;
    fd.f22 = (x0 * y1 - x1 * y0) / det;

    fd.iz0 = 1.0f / z0; fd.iz1 = 1.0f / z1; fd.iz2 = 1.0f / z2;
    fd.z0 = z0; fd.z1 = z1; fd.z2 = z2;
    return fd;
}

__global__ __launch_bounds__(RW * RH) void raster_kernel(
    const float* __restrict__ faces,
    const float* __restrict__ textures,
    float* __restrict__ out)
{
    __shared__ FaceData sf[CAP];
    __shared__ unsigned short sidx[F_CNT];
    __shared__ int scount;

    const int b   = blockIdx.z;
    const int rx0 = blockIdx.x * RW;
    const int ry0 = blockIdx.y * RH;
    const int tid = threadIdx.y * RW + threadIdx.x;   // [0, 512)

    if (tid == 0) scount = 0;
    __syncthreads();

    // region bbox in NDC (pixel centers): coord = (2*i + 1 - IS) / IS
    const float xlo = (2.0f * rx0            + 1.0f - IS) / (float)IS;
    const float xhi = (2.0f * (rx0 + RW - 1) + 1.0f - IS) / (float)IS;
    const float ylo = (2.0f * ry0            + 1.0f - IS) / (float)IS;
    const float yhi = (2.0f * (ry0 + RH - 1) + 1.0f - IS) / (float)IS;

    // ---- scan faces (exactly 1 per thread), compact overlapping front faces ----
    {
        const int f = tid;  // F_CNT == RW*RH == 512
        const float* v = faces + ((size_t)b * F_CNT + f) * 9;
        const float x0 = v[0], y0 = v[1];
        const float x1 = v[3], y1 = v[4];
        const float x2 = v[6], y2 = v[7];

        // backface cull: front iff (y2-y0)*(x1-x0) >= (x2-x0)*(y1-y0)
        const bool front = (y2 - y0) * (x1 - x0) >= (x2 - x0) * (y1 - y0);

        const float bxmin = fminf(x0, fminf(x1, x2));
        const float bxmax = fmaxf(x0, fmaxf(x1, x2));
        const float bymin = fminf(y0, fminf(y1, y2));
        const float bymax = fmaxf(y0, fmaxf(y1, y2));

        const bool keep = front &&
                          bxmin <= xhi && bxmax >= xlo &&
                          bymin <= yhi && bymax >= ylo;
        if (keep) {
            const int slot = atomicAdd(&scount, 1);
            sidx[slot] = (unsigned short)f;
            if (slot < CAP) sf[slot] = make_face(v);
        }
    }
    __syncthreads();

    // ---- per-pixel rasterization ----
    const int px = rx0 + threadIdx.x;
    const int py = ry0 + threadIdx.y;
    const float xp = (2.0f * px + 1.0f - IS) / (float)IS;
    const float yp = (2.0f * py + 1.0f - IS) / (float)IS;

    float best = FARF;
    int bestf = -1;
    float bw0 = 0.0f, bw1 = 0.0f, bw2 = 0.0f;
    float bz0 = 1.0f, bz1 = 1.0f, bz2 = 1.0f;

    // selection uses the (zp, f) total order so the result is independent
    // of the (atomic, unordered) compaction order
    auto process = [&](const FaceData& fd, const int f) {
        if (xp < fd.xmin || xp > fd.xmax || yp < fd.ymin || yp > fd.ymax) return;

        const bool in01 = (yp - fd.y0) * (fd.x1 - fd.x0) >= (xp - fd.x0) * (fd.y1 - fd.y0);
        const bool in12 = (yp - fd.y1) * (fd.x2 - fd.x1) >= (xp - fd.x1) * (fd.y2 - fd.y1);
        const bool in20 = (yp - fd.y2) * (fd.x0 - fd.x2) >= (xp - fd.x2) * (fd.y0 - fd.y2);
        if (!(in01 && in12 && in20)) return;

        float w0 = fd.f00 * xp + fd.f01 * yp + fd.f02;
        float w1 = fd.f10 * xp + fd.f11 * yp + fd.f12;
        float w2 = fd.f20 * xp + fd.f21 * yp + fd.f22;
        w0 = fminf(fmaxf(w0, 0.0f), 1.0f);
        w1 = fminf(fmaxf(w1, 0.0f), 1.0f);
        w2 = fminf(fmaxf(w2, 0.0f), 1.0f);
        const float ws = fmaxf(w0 + w1 + w2, 1e-12f);
        w0 = w0 / ws; w1 = w1 / ws; w2 = w2 / ws;

        const float s = w0 * fd.iz0 + w1 * fd.iz1 + w2 * fd.iz2;
        const float zp = 1.0f / fmaxf(s, 1e-12f);

        if (zp > NEARF && zp < FARF) {
            if (zp < best || (zp == best && f < bestf)) {
                best = zp; bestf = f;
                bw0 = w0; bw1 = w1; bw2 = w2;
                bz0 = fd.z0; bz1 = fd.z1; bz2 = fd.z2;
            }
        }
    };

    const int cnt = scount;
    const int ncached = (cnt < CAP) ? cnt : CAP;
    for (int i = 0; i < ncached; ++i)
        process(sf[i], sidx[i]);
    for (int i = CAP; i < cnt; ++i) {  // overflow fallback (never taken for this input)
        const int f = sidx[i];
        const FaceData fd = make_face(faces + ((size_t)b * F_CNT + f) * 9);
        process(fd, f);
    }

    // ---- texture-cube trilinear sampling for the winning face ----
    float r = 0.0f, g = 0.0f, bc = 0.0f;
    if (bestf >= 0) {
        // tif = (w * (T-1)) * (depth / z)  -- same assoc order as reference
        float t0 = bw0 * 3.0f * (best / bz0);
        float t1 = bw1 * 3.0f * (best / bz1);
        float t2 = bw2 * 3.0f * (best / bz2);
        const float tmax = 2.999f;  // T - 1 - EPS
        t0 = fminf(fmaxf(t0, 0.0f), tmax);
        t1 = fminf(fmaxf(t1, 0.0f), tmax);
        t2 = fminf(fmaxf(t2, 0.0f), tmax);
        const float fl0 = floorf(t0), fl1 = floorf(t1), fl2 = floorf(t2);
        const float fr0 = t0 - fl0, fr1 = t1 - fl1, fr2 = t2 - fl2;
        const int i0 = (int)fl0, i1 = (int)fl1, i2 = (int)fl2;

        const float* tex = textures + ((size_t)b * F_CNT + bestf) * (TEX * TEX * TEX * 3);
        #pragma unroll
        for (int c = 0; c < 8; ++c) {
            const int b0 = c & 1, b1 = (c >> 1) & 1, b2 = (c >> 2) & 1;
            const float cw = (b0 ? fr0 : 1.0f - fr0)
                           * (b1 ? fr1 : 1.0f - fr1)
                           * (b2 ? fr2 : 1.0f - fr2);
            const float* sp = tex + (((size_t)(i0 + b0) * TEX + (i1 + b1)) * TEX + (i2 + b2)) * 3;
            r  += cw * sp[0];
            g  += cw * sp[1];
            bc += cw * sp[2];
        }
    }

    // ---- writes: rgb [B,IS,IS,3] | alpha [B,1,IS,IS] | depth [B,IS,IS] ----
    const size_t pix = (size_t)py * IS + px;
    const size_t bp  = (size_t)b * IS * IS + pix;

    out[bp * 3 + 0] = r;
    out[bp * 3 + 1] = g;
    out[bp * 3 + 2] = bc;

    float* alpha = out + (size_t)2 * IS * IS * 3;   // after rgb (both batches)
    alpha[bp] = (bestf >= 0) ? 1.0f : 0.0f;

    float* depth = alpha + (size_t)2 * IS * IS;
    depth[bp] = best;  // FAR when no face found
}

extern "C" void kernel_launch(void* const* d_in, const int* in_sizes, int n_in,
                              void* d_out, int out_size, void* d_ws, size_t ws_size,
                              hipStream_t stream) {
    const float* faces    = (const float*)d_in[0];
    const float* textures = (const float*)d_in[1];
    float* out = (float*)d_out;

    const int B = in_sizes[0] / (F_CNT * 9);  // = 2

    dim3 grid(IS / RW, IS / RH, B);           // 6 x 12 x 2 = 144 blocks
    dim3 block(RW, RH, 1);                    // 512 threads
    raster_kernel<<<grid, block, 0, stream>>>(faces, textures, out);
}